// Round 21
// baseline (70.561 us; speedup 1.0000x reference)
//
#include <hip/hip_runtime.h>
#include <hip/hip_bf16.h>
#include <math.h>

#define DMODEL 512
#define NSEQ 2048
#define NHEAD 8
#define DK 64
#define DV 64
#define MFEAT 266
#define MPAD 288        // padded feature dim for bf16 MFMA (zero tail), mult of 32
#define NT 32           // number of chunks (chunk = 64)
#define LN_EPS 1e-6f
#define KERNEL_EPS 1e-4f
#define NORM_STAB 1e-6f
#define SCALE 0.21022410381342863f  // 512^-0.25

typedef __attribute__((ext_vector_type(8))) short short8;
typedef __attribute__((ext_vector_type(4))) short sv4;
typedef __attribute__((ext_vector_type(4))) float f32x4;

// Compiler-native bf16 RNE cast (fuses to v_cvt_pk_bf16_f32; m240: don't hand-roll)
__device__ inline short f2bf(float f) {
    return (short)__bfloat16_as_ushort(__float2bfloat16(f));
}
__device__ inline float bf2f(short s) {
    unsigned u = ((unsigned)(unsigned short)s) << 16;
    return __builtin_bit_cast(float, u);
}

// ---------------- prep: weights -> bf16 [n][k] (SCALE folded); rf -> bf16 [MPAD][64] zero-padded ----------------
__global__ __launch_bounds__(256) void prep_kernel(const float* __restrict__ Wq,
                                                   const float* __restrict__ Wk,
                                                   const float* __restrict__ Wv,
                                                   const float* __restrict__ Wfc,
                                                   const float* __restrict__ rf,
                                                   short* __restrict__ Wqt,
                                                   short* __restrict__ Wkt,
                                                   short* __restrict__ Wvt,
                                                   short* __restrict__ Wfct,
                                                   short* __restrict__ rfb) {
    int wsel = blockIdx.z;
    int tid = threadIdx.x;
    if (wsel == 4) {
        if (blockIdx.x != 0) return;
        int r0 = blockIdx.y * 36;
        for (int lp = 0; lp < 9; ++lp) {
            int c = tid + lp * 256;          // 2304 = 36 rows * 64 cols
            int r = r0 + c / 64, d = c % 64;
            float v = (r < MFEAT) ? rf[(size_t)r * DK + d] : 0.f;
            rfb[(size_t)r * DK + d] = f2bf(v);
        }
        return;
    }
    __shared__ short T[64][65];
    int k0 = blockIdx.x * 64, n0 = blockIdx.y * 64;
    const float* W = (wsel == 0) ? Wq : (wsel == 1) ? Wk : (wsel == 2) ? Wv : Wfc;
    short* Wt = (wsel == 0) ? Wqt : (wsel == 1) ? Wkt : (wsel == 2) ? Wvt : Wfct;
    float scale = (wsel <= 1) ? SCALE : 1.f;
    for (int lp = 0; lp < 4; ++lp) {
        int c = tid + lp * 256;             // 1024 = 64 k-rows * 16 n-quads
        int kk = c >> 4, q4 = (c & 15) * 4;
        f32x4 v = *(const f32x4*)&W[(size_t)(k0 + kk) * DMODEL + n0 + q4];
        for (int j = 0; j < 4; ++j) T[q4 + j][kk] = f2bf(v[j] * scale);
    }
    __syncthreads();
    for (int lp = 0; lp < 2; ++lp) {
        int c = tid + lp * 256;             // 512 = 64 n-rows * 8 k-chunks
        int nn = c >> 3, c8 = c & 7;
        short8 v = *(const short8*)&T[nn][c8 * 8];
        *(short8*)&Wt[(size_t)(n0 + nn) * DMODEL + k0 + c8 * 8] = v;
    }
}

// ============ fused QKV GEMM + random-feature map — 32-ROW TILES ============
// grid (nt=64, h=8, z=3) = 1536 blocks (6/CU: R20 post-mortem showed 768 blocks
// = 3/CU was the latency wall; per-stage cost is tile-height-independent).
// LDS 19.7KB. Wave w: GEMM row-frag rt=w&1, col-pair w>>1; feat n-block w&1,
// m-tiles == (w>>1) mod 2.
__global__ __launch_bounds__(256) void qkvfeat_kernel(const float* __restrict__ qx,
                                                      const float* __restrict__ kx,
                                                      const float* __restrict__ vx,
                                                      const short* __restrict__ Wqt,
                                                      const short* __restrict__ Wkt,
                                                      const short* __restrict__ Wvt,
                                                      const float* __restrict__ gamma,
                                                      const float* __restrict__ beta,
                                                      const short* __restrict__ rfb,
                                                      short* __restrict__ vh,
                                                      short* __restrict__ qp,
                                                      short* __restrict__ kp) {
    __shared__ __align__(16) char smem[19712];
    auto AsB = (short(*)[40])smem;             // [2*32][40] dbuf A (buf*32+row)
    auto BsB = (short(*)[40])(smem + 5120);    // [2*64][40] dbuf B (buf*64+n)
    auto Xs = (short(*)[72])smem;              // [32][72] feat input (overlay)
    short* kpl = (short*)smem;                 // [32][300] output staging (overlay)
    float* hks = (float*)(smem + 19200);       // 32 floats
    float* hpart = (float*)(smem + 19328);     // [32][2] floats

    int z = blockIdx.z;
    const float* A = (z == 0) ? qx : (z == 1) ? kx : vx;
    const short* Bt = (z == 0) ? Wqt : (z == 1) ? Wkt : Wvt;
    int nt = blockIdx.x, h = blockIdx.y;
    int bm = nt * 32, bn = h * 64;
    int tid = threadIdx.x;
    int wid = tid >> 6, lane = tid & 63;
    int fr = lane & 15, fq = (lane >> 4) * 8;
    int rt = wid & 1, cfb = (wid >> 1) * 2;    // GEMM row-frag, col-frag base
    f32x4 acc[2] = {f32x4{0,0,0,0}, f32x4{0,0,0,0}};
    int arow = tid >> 3, ak = tid & 7;         // A staging: 32 rows x 8 threads
    int nrow = tid >> 2, bk = (tid & 3) * 8;   // B staging: 64 n x 4 threads
    float lnm = 0.f, lnr = 0.f;
    if (z == 0) {
        // LN stats: 8 threads per row, 64 elements each
        const float* xr = qx + (size_t)(bm + arow) * DMODEL + ak * 64;
        float s = 0.f, ss = 0.f;
#pragma unroll 4
        for (int i = 0; i < 64; i += 4) {
            f32x4 vv = *(const f32x4*)(xr + i);
            s += vv[0] + vv[1] + vv[2] + vv[3];
            ss += vv[0]*vv[0] + vv[1]*vv[1] + vv[2]*vv[2] + vv[3]*vv[3];
        }
        s += __shfl_xor(s, 1); s += __shfl_xor(s, 2); s += __shfl_xor(s, 4);
        ss += __shfl_xor(ss, 1); ss += __shfl_xor(ss, 2); ss += __shfl_xor(ss, 4);
        float m = s / (float)DMODEL;
        float var = ss / (float)DMODEL - m * m;
        lnm = m;
        lnr = rsqrtf(var + LN_EPS);
    }
    auto loadA = [&](int k0) -> sv4 {
        f32x4 v0 = *(const f32x4*)&A[(size_t)(bm + arow) * DMODEL + k0 + ak * 4];
        sv4 sv;
        if (z == 0) {
            f32x4 g0 = *(const f32x4*)&gamma[k0 + ak * 4];
            f32x4 b0 = *(const f32x4*)&beta[k0 + ak * 4];
            for (int j = 0; j < 4; ++j)
                sv[j] = f2bf((v0[j] - lnm) * lnr * g0[j] + b0[j]);
        } else {
            for (int j = 0; j < 4; ++j) sv[j] = f2bf(v0[j]);
        }
        return sv;
    };
    auto loadB = [&](int k0) -> short8 {
        return *(const short8*)&Bt[(size_t)(bn + nrow) * DMODEL + k0 + bk];
    };
    sv4 aReg = loadA(0);
    short8 bReg = loadB(0);
    int buf = 0;
#pragma unroll 2
    for (int k0 = 0; k0 < DMODEL; k0 += 32) {
        *(sv4*)&AsB[buf * 32 + arow][ak * 4] = aReg;
        *(short8*)&BsB[buf * 64 + nrow][bk] = bReg;
        __syncthreads();
        if (k0 + 32 < DMODEL) { aReg = loadA(k0 + 32); bReg = loadB(k0 + 32); }
        short8 a = *(const short8*)&AsB[buf * 32 + rt * 16 + fr][fq];
        for (int nf = 0; nf < 2; ++nf) {
            short8 b = *(const short8*)&BsB[buf * 64 + (cfb + nf) * 16 + fr][fq];
            acc[nf] = __builtin_amdgcn_mfma_f32_16x16x32_bf16(a, b, acc[nf], 0, 0, 0);
        }
        buf ^= 1;
    }
    __syncthreads();   // GEMM LDS done
    if (z == 2) {
        for (int nf = 0; nf < 2; ++nf) {
            int col = bn + (cfb + nf) * 16 + fr;
            for (int j = 0; j < 4; ++j) {
                int row = bm + rt * 16 + (lane >> 4) * 4 + j;
                vh[(size_t)row * DMODEL + col] = f2bf(acc[nf][j]);
            }
        }
        return;
    }
    // feat: C tile -> Xs (bf16), h_k partials (wave-pair combine via hpart)
    for (int nf = 0; nf < 2; ++nf) {
        int col = (cfb + nf) * 16 + fr;
        for (int j = 0; j < 4; ++j)
            Xs[rt * 16 + (lane >> 4) * 4 + j][col] = f2bf(acc[nf][j]);
    }
    if (z == 1) {
        for (int j = 0; j < 4; ++j) {
            float ss = acc[0][j] * acc[0][j] + acc[1][j] * acc[1][j];
            for (int o = 1; o < 16; o <<= 1) ss += __shfl_xor(ss, o);
            if (fr == 0) hpart[(rt * 16 + (lane >> 4) * 4 + j) * 2 + (wid >> 1)] = ss;
        }
    }
    __syncthreads();
    if (z == 1 && tid < 32)
        hks[tid] = -0.5f * (hpart[tid * 2] + hpart[tid * 2 + 1]);
    __syncthreads();

    int nb = wid & 1, mpar = wid >> 1;
    int n_loc = nb * 16 + fr;
    short8 xb0 = *(const short8*)&Xs[n_loc][fq];
    short8 xb1 = *(const short8*)&Xs[n_loc][32 + fq];
    float hval = (z == 1) ? hks[n_loc] : 0.f;
    __syncthreads();  // xb/hks reads done; Xs region becomes kpl

    short (*kpl2)[300] = (short(*)[300])kpl;
    const float cnorm = 0.06131393394849658f;  // 266^-0.5
#pragma unroll
    for (int t = 0; t < 9; ++t) {
        int mt = mpar + 2 * t;
        int row = mt * 16 + fr;
        short8 a0 = *(const short8*)&rfb[(size_t)row * DK + fq];
        short8 a1 = *(const short8*)&rfb[(size_t)row * DK + 32 + fq];
        f32x4 facc = {0.f, 0.f, 0.f, 0.f};
        facc = __builtin_amdgcn_mfma_f32_16x16x32_bf16(a0, xb0, facc, 0, 0, 0);
        facc = __builtin_amdgcn_mfma_f32_16x16x32_bf16(a1, xb1, facc, 0, 0, 0);
        sv4 o;
        for (int j = 0; j < 4; ++j) {
            int m = mt * 16 + (lane >> 4) * 4 + j;
            float val = (m < MFEAT) ? cnorm * (__expf(facc[j] + hval) + KERNEL_EPS) : 0.f;
            o[j] = f2bf(val);
        }
        *(sv4*)&kpl2[n_loc][mt * 16 + (lane >> 4) * 4] = o;
    }
    __syncthreads();
    short* outp = (z == 0) ? qp : kp;
    for (int lp = 0; lp < 5; ++lp) {
        int c = tid + lp * 256;      // 1152 = 32 rows * 36 chunks
        if (c < 1152) {
            int nn = c / 36, c8 = c % 36;
            short8 v = *(const short8*)&kpl2[nn][c8 * 8];
            *(short8*)&outp[((size_t)h * NSEQ + bm + nn) * MPAD + c8 * 8] = v;
        }
    }
}

// ---------------- phase A (MFMA): per-chunk sums -> bf16 KVc[(h,t,dv)][m], fp32 Ks[(h,t)][m] ----------------
__global__ __launch_bounds__(256) void chunksum_kernel(const short* __restrict__ kp,
                                                       const short* __restrict__ vh,
                                                       short* __restrict__ KVc,
                                                       float* __restrict__ Ks) {
    int t = blockIdx.x, h = blockIdx.y;
    __shared__ short kpT[288 * 72];   // [m][i-swizzled], stride 72 shorts; 41.5KB
    __shared__ short Vt[64][72];      // [dv][i]
    int tid = threadIdx.x;
    int w = tid >> 6, l = tid & 63;
    int fr = l & 15, fq8 = (l >> 4) * 8;
    const short* kpb = kp + ((size_t)h * NSEQ + (size_t)t * 64) * MPAD;

    for (int lp = 0; lp < 9; ++lp) {
        int c = tid + lp * 256;       // 2304 = 64 i * 36 m-chunks
        int i = c / 36, c8 = c % 36;
        short8 v = *(const short8*)&kpb[(size_t)i * MPAD + c8 * 8];
        int i8 = i >> 3, i7 = i & 7;
        for (int jj = 0; jj < 8; ++jj) {
            int m = c8 * 8 + jj;
            int ig = i8 ^ ((m >> 3) & 7);
            kpT[m * 72 + ig * 8 + i7] = v[jj];
        }
    }
    for (int lp = 0; lp < 2; ++lp) {
        int c = tid + lp * 256;       // 512 = 64 i * 8 d-chunks
        int i = c & 63, d8 = (c >> 6) * 8;
        short8 v = *(const short8*)&vh[(size_t)(t * 64 + i) * DMODEL + h * DV + d8];
        for (int jj = 0; jj < 8; ++jj) Vt[d8 + jj][i] = v[jj];
    }
    __syncthreads();

    f32x4 acc[5][4];
#pragma unroll
    for (int tt = 0; tt < 5; ++tt)
        for (int nf = 0; nf < 4; ++nf) acc[tt][nf] = f32x4{0, 0, 0, 0};
#pragma unroll
    for (int tt = 0; tt < 5; ++tt) {
        int tr = w + tt * 4;
        if (tr < 18) {
            int row = tr * 16 + fr;
            int swz = (row >> 3) & 7;
            short8 a0 = *(const short8*)&kpT[row * 72 + (((fq8 >> 3)) ^ swz) * 8];
            short8 a1 = *(const short8*)&kpT[row * 72 + ((4 + (fq8 >> 3)) ^ swz) * 8];
            for (int nf = 0; nf < 4; ++nf) {
                short8 b0 = *(const short8*)&Vt[nf * 16 + fr][fq8];
                short8 b1 = *(const short8*)&Vt[nf * 16 + fr][32 + fq8];
                acc[tt][nf] = __builtin_amdgcn_mfma_f32_16x16x32_bf16(a0, b0, acc[tt][nf], 0, 0, 0);
                acc[tt][nf] = __builtin_amdgcn_mfma_f32_16x16x32_bf16(a1, b1, acc[tt][nf], 0, 0, 0);
            }
        }
    }
    for (int m = tid; m < MPAD; m += 256) {
        int swz = (m >> 3) & 7;
        float s = 0.f;
        for (int i8 = 0; i8 < 8; ++i8) {
            int ig = i8 ^ swz;
            for (int j = 0; j < 8; ++j) s += bf2f(kpT[m * 72 + ig * 8 + j]);
        }
        Ks[((size_t)h * NT + t) * MPAD + m] = s;
    }
    __syncthreads();  // kpT reads done; overlay kvT
    short* kvT = kpT; // [64 dv][296 m]
#pragma unroll
    for (int tt = 0; tt < 5; ++tt) {
        int tr = w + tt * 4;
        if (tr < 18) {
            for (int nf = 0; nf < 4; ++nf) {
                int dv = nf * 16 + fr;
                for (int j = 0; j < 4; ++j) {
                    int m = tr * 16 + (l >> 4) * 4 + j;
                    kvT[dv * 296 + m] = f2bf(acc[tt][nf][j]);
                }
            }
        }
    }
    __syncthreads();
    for (int lp = 0; lp < 9; ++lp) {
        int c = tid + lp * 256;       // 2304 = 64 dv * 36
        int dv = c / 36, c8 = c % 36;
        short8 v = *(const short8*)&kvT[dv * 296 + c8 * 8];
        *(short8*)&KVc[(((size_t)h * NT + t) * DV + dv) * MPAD + c8 * 8] = v;
    }
}

// ---------------- fused exclusive chunk-scans, batched loads ----------------
__global__ __launch_bounds__(256) void scan_kernel(const short* __restrict__ KVc,
                                                   short* __restrict__ KVbT,
                                                   float* __restrict__ Ks,
                                                   float* __restrict__ Ktot) {
    int idx = blockIdx.x * 256 + threadIdx.x;
    const int NKV = NHEAD * DV * MPAD;       // 147456
    if (idx < NKV) {
        int h = idx / (DV * MPAD);
        int rem = idx % (DV * MPAD);
        size_t base = (size_t)h * NT * DV * MPAD + rem;
        short vals[NT];
#pragma unroll
        for (int t = 0; t < NT; ++t) vals[t] = KVc[base + (size_t)t * DV * MPAD];
        float run = 0.f;
#pragma unroll
        for (int t = 0; t < NT; ++t) {
            KVbT[base + (size_t)t * DV * MPAD] = f2bf(run);
            run += bf2f(vals[t]);
        }
    } else {
        int j = idx - NKV;
        if (j < NHEAD * MPAD) {
            int h = j / MPAD, m = j % MPAD;
            size_t base = (size_t)h * NT * MPAD + m;
            float vals[NT];
#pragma unroll
            for (int t = 0; t < NT; ++t) vals[t] = Ks[base + (size_t)t * MPAD];
            float run = 0.f;
#pragma unroll
            for (int t = 0; t < NT; ++t) {
                Ks[base + (size_t)t * MPAD] = run;
                run += vals[t];
            }
            Ktot[(size_t)h * MPAD + m] = run;
        }
    }
}

// ---------------- phase C: MFMA intra+inter+denominators; bf16 out ----------------
__global__ __launch_bounds__(256) void phasec_kernel(const short* __restrict__ qp,
                                                     const short* __restrict__ kp,
                                                     const short* __restrict__ vh,
                                                     const short* __restrict__ KVbT,
                                                     const float* __restrict__ Ks,
                                                     const float* __restrict__ Ktot,
                                                     short* __restrict__ attn) {
    int t = blockIdx.x, h = blockIdx.y;
    __shared__ short Buf[64][296];   // Kp (QK^T phase) then St (inter phase)
    __shared__ short Vt[64][72];     // [dv][i]
    __shared__ short Am[64][72];     // masked A, bf16
    __shared__ float Ksp[MPAD], Ktp[MPAD];
    __shared__ float fscale_s[64];
    int tid = threadIdx.x;
    int w = tid >> 6, l = tid & 63;
    int fr = l & 15, fq = (l >> 4) * 8;
    const short* qpb = qp + ((size_t)h * NSEQ + (size_t)t * 64) * MPAD;
    const short* kpb = kp + ((size_t)h * NSEQ + (size_t)t * 64) * MPAD;
    const short* stb = KVbT + ((size_t)h * NT + t) * DV * MPAD;

    short8 qf[9];
#pragma unroll
    for (int ks = 0; ks < 9; ++ks)
        qf[ks] = *(const short8*)&qpb[(size_t)(w * 16 + fr) * MPAD + ks * 32 + fq];

    int srow = tid >> 2, sc4 = tid & 3;
#pragma unroll
    for (int lp = 0; lp < 9; ++lp) {
        int c = sc4 + lp * 4;
        *(short8*)&Buf[srow][c * 8] = *(const short8*)&kpb[(size_t)srow * MPAD + c * 8];
    }
    for (int lp = 0; lp < 2; ++lp) {
        int c = tid + lp * 256;
        int i = c & 63, d8 = (c >> 6) * 8;
        short8 v = *(const short8*)&vh[(size_t)(t * 64 + i) * DMODEL + h * DV + d8];
        for (int jj = 0; jj < 8; ++jj) Vt[d8 + jj][i] = v[jj];
    }
    for (int idx = tid; idx < MPAD; idx += 256) {
        Ksp[idx] = Ks[((size_t)h * NT + t) * MPAD + idx];
        Ktp[idx] = Ktot[(size_t)h * MPAD + idx];
    }
    short8 stg[9];
#pragma unroll
    for (int lp = 0; lp < 9; ++lp) {
        int c = sc4 + lp * 4;
        stg[lp] = *(const short8*)&stb[(size_t)srow * MPAD + c * 8];
    }
    __syncthreads();

    f32x4 accA[4] = {f32x4{0,0,0,0}, f32x4{0,0,0,0}, f32x4{0,0,0,0}, f32x4{0,0,0,0}};
    f32x4 accO[4] = {f32x4{0,0,0,0}, f32x4{0,0,0,0}, f32x4{0,0,0,0}, f32x4{0,0,0,0}};
#pragma unroll 3
    for (int ks = 0; ks < 9; ++ks) {
        int ko = ks * 32 + fq;
        for (int nf = 0; nf < 4; ++nf) {
            short8 bk = *(const short8*)&Buf[nf * 16 + fr][ko];
            accA[nf] = __builtin_amdgcn_mfma_f32_16x16x32_bf16(qf[ks], bk, accA[nf], 0, 0, 0);
        }
    }
    __syncthreads();
#pragma unroll
    for (int lp = 0; lp < 9; ++lp) {
        int c = sc4 + lp * 4;
        *(short8*)&Buf[srow][c * 8] = stg[lp];
    }
    for (int nf = 0; nf < 4; ++nf) {
        int col = nf * 16 + fr;
        for (int j = 0; j < 4; ++j) {
            int row = w * 16 + (l >> 4) * 4 + j;
            Am[row][col] = (col <= row) ? f2bf(accA[nf][j]) : (short)0;
        }
    }
    __syncthreads();
#pragma unroll 3
    for (int ks = 0; ks < 9; ++ks) {
        int ko = ks * 32 + fq;
        for (int nf = 0; nf < 4; ++nf) {
            short8 bs = *(const short8*)&Buf[nf * 16 + fr][ko];
            accO[nf] = __builtin_amdgcn_mfma_f32_16x16x32_bf16(qf[ks], bs, accO[nf], 0, 0, 0);
        }
    }
#pragma unroll
    for (int ks = 0; ks < 2; ++ks) {
        int ko = ks * 32 + fq;
        short8 a = *(const short8*)&Am[w * 16 + fr][ko];
        for (int nf = 0; nf < 4; ++nf) {
            short8 b = *(const short8*)&Vt[nf * 16 + fr][ko];
            accO[nf] = __builtin_amdgcn_mfma_f32_16x16x32_bf16(a, b, accO[nf], 0, 0, 0);
        }
    }
    int di = tid >> 2, dp = tid & 3;
    float dc = 0.f, df = 0.f;
    {
        const short* amrow = &Am[di][dp * 16];
        short8 s0 = *(const short8*)amrow;
        short8 s1 = *(const short8*)(amrow + 8);
        for (int j2 = 0; j2 < 8; ++j2) dc += bf2f(s0[j2]) + bf2f(s1[j2]);
    }
#pragma unroll
    for (int c8 = 0; c8 < 9; ++c8) {
        int m = dp * 72 + c8 * 8;
        short8 qv = *(const short8*)&qpb[(size_t)di * MPAD + m];
        for (int j2 = 0; j2 < 8; ++j2) {
            float qq = bf2f(qv[j2]);
            dc += qq * Ksp[m + j2];
            df += qq * Ktp[m + j2];
        }
    }
    dc += __shfl_xor(dc, 1); dc += __shfl_xor(dc, 2);
    df += __shfl_xor(df, 1); df += __shfl_xor(df, 2);
    if (dp == 0) {
        float dst = df;
        if (fabsf(dst) <= NORM_STAB) dst += 2.f * NORM_STAB;
        fscale_s[di] = (1.f / dc) / dst;
    }
    __syncthreads();
    for (int nf = 0; nf < 4; ++nf) {
        int col = nf * 16 + fr;
        for (int j = 0; j < 4; ++j) {
            int row = w * 16 + (l >> 4) * 4 + j;
            attn[((size_t)t * 64 + row) * DMODEL + h * DV + col] =
                f2bf(accO[nf][j] * fscale_s[row]);
        }
    }
}

// ---------------- final GEMM with bias + residual (depth-2 pipelined) ----------------
__global__ __launch_bounds__(256) void fgemm_kernel(const short* __restrict__ A,
                                                    const short* __restrict__ Bt,
                                                    float* __restrict__ C,
                                                    const float* __restrict__ bias,
                                                    const float* __restrict__ residual) {
    __shared__ short AsB[128][40];
    __shared__ short BsB[128][40];
    int bm = blockIdx.y * 64, bn = blockIdx.x * 64;
    int tid = threadIdx.x;
    int wid = tid >> 6, lane = tid & 63;
    f32x4 acc[4] = {f32x4{0,0,0,0}, f32x4{0,0,0,0}, f32x4{0,0,0,0}, f32x4{0,0,0,0}};
    int ar = tid >> 2, akq = tid & 3;
    auto ldA = [&](int k0) { return *(const short8*)&A[(size_t)(bm + ar) * DMODEL + k0 + akq * 8]; };
    auto ldB = [&](int k0) { return *(const short8*)&Bt[(size_t)(bn + ar) * DMODEL + k0 + akq * 8]; };
    short8 aR0 = ldA(0), bR0 = ldB(0);
    short8 aR1 = ldA(32), bR1 = ldB(32);
    int buf = 0;
#pragma unroll 2
    for (int k0 = 0; k0 < DMODEL; k0 += 32) {
        int slot = (k0 >> 5) & 1;
        if (slot == 0) {
            *(short8*)&AsB[buf * 64 + ar][akq * 8] = aR0;
            *(short8*)&BsB[buf * 64 + ar][akq * 8] = bR0;
        } else {
            *(short8*)&AsB[buf * 64 + ar][akq * 8] = aR1;
            *(short8*)&BsB[buf * 64 + ar][akq * 8] = bR1;
        }
        __syncthreads();
        if (k0 + 64 < DMODEL) {
            if (slot == 0) { aR0 = ldA(k0 + 64); bR0 = ldB(k0 + 64); }
            else           { aR1 = ldA(k0 + 64); bR1 = ldB(k0 + 64); }
        }
        int row = buf * 64 + wid * 16 + (lane & 15);
        int koff = (lane >> 4) * 8;
        short8 a = *(const short8*)&AsB[row][koff];
        for (int nf = 0; nf < 4; ++nf) {
            int col = buf * 64 + nf * 16 + (lane & 15);
            short8 b = *(const short8*)&BsB[col][koff];
            acc[nf] = __builtin_amdgcn_mfma_f32_16x16x32_bf16(a, b, acc[nf], 0, 0, 0);
        }
        buf ^= 1;
    }
    for (int nf = 0; nf < 4; ++nf) {
        int col = bn + nf * 16 + (lane & 15);
        for (int j = 0; j < 4; ++j) {
            int row = bm + wid * 16 + (lane >> 4) * 4 + j;
            C[(size_t)row * DMODEL + col] =
                acc[nf][j] + bias[col] + residual[(size_t)row * DMODEL + col];
        }
    }
}

extern "C" void kernel_launch(void* const* d_in, const int* in_sizes, int n_in,
                              void* d_out, int out_size, void* d_ws, size_t ws_size,
                              hipStream_t stream) {
    const float* q = (const float*)d_in[0];
    const float* k = (const float*)d_in[1];
    const float* v = (const float*)d_in[2];
    const float* Wq = (const float*)d_in[3];
    const float* Wk = (const float*)d_in[4];
    const float* Wv = (const float*)d_in[5];
    const float* Wfc = (const float*)d_in[6];
    const float* bfc = (const float*)d_in[7];
    const float* gamma = (const float*)d_in[8];
    const float* beta = (const float*)d_in[9];
    const float* rf = (const float*)d_in[10];
    float* out = (float*)d_out;

    float* ws = (float*)d_ws;
    short* attn = (short*)ws;                              // bf16 2048*512
    short* vhb = attn + (size_t)NSEQ * DMODEL;             // bf16 2048*512
    short* qp = vhb + (size_t)NSEQ * DMODEL;               // bf16 8*2048*288
    short* kp = qp + (size_t)NHEAD * NSEQ * MPAD;
    short* KVc = kp + (size_t)NHEAD * NSEQ * MPAD;         // bf16 8*32*64*288
    short* KVbT = KVc + (size_t)NHEAD * NT * DV * MPAD;
    float* Ks = (float*)(KVbT + (size_t)NHEAD * NT * DV * MPAD);   // fp32 8*32*288
    float* Ktot = Ks + (size_t)NHEAD * NT * MPAD;          // 8*288
    short* Wqt = (short*)(Ktot + (size_t)NHEAD * MPAD);    // bf16 512*512 each
    short* Wkt = Wqt + (size_t)DMODEL * DMODEL;
    short* Wvt = Wkt + (size_t)DMODEL * DMODEL;
    short* Wfct = Wvt + (size_t)DMODEL * DMODEL;
    short* rfb = Wfct + (size_t)DMODEL * DMODEL;           // bf16 288*64

    dim3 gp(8, 8, 5);
    prep_kernel<<<gp, 256, 0, stream>>>(Wq, Wk, Wv, Wfc, rf, Wqt, Wkt, Wvt, Wfct, rfb);
    dim3 gq(NSEQ / 32, NHEAD, 3);
    qkvfeat_kernel<<<gq, 256, 0, stream>>>(q, k, v, Wqt, Wkt, Wvt, gamma, beta, rfb,
                                           vhb, qp, kp);
    dim3 ga(NT, NHEAD);
    chunksum_kernel<<<ga, 256, 0, stream>>>(kp, vhb, KVc, Ks);
    int scan_threads = NHEAD * DV * MPAD + NHEAD * MPAD;
    scan_kernel<<<(scan_threads + 255) / 256, 256, 0, stream>>>(KVc, KVbT, Ks, Ktot);
    dim3 gc(NT, NHEAD);
    phasec_kernel<<<gc, 256, 0, stream>>>(qp, kp, vhb, KVbT, Ks, Ktot, attn);
    dim3 g(DMODEL / 64, NSEQ / 64);
    fgemm_kernel<<<g, 256, 0, stream>>>(attn, Wfct, out, bfc, q);
}

// Round 22
// 70.251 us; speedup vs baseline: 1.0044x; 1.0044x over previous
//
#include <hip/hip_runtime.h>
#include <hip/hip_bf16.h>
#include <math.h>

#define DMODEL 512
#define NSEQ 2048
#define NHEAD 8
#define DK 64
#define DV 64
#define MFEAT 266
#define MPAD 288        // padded feature dim for bf16 MFMA (zero tail), mult of 32
#define NT 32           // number of chunks (chunk = 64)
#define LN_EPS 1e-6f
#define KERNEL_EPS 1e-4f
#define NORM_STAB 1e-6f
#define SCALE 0.21022410381342863f  // 512^-0.25

typedef __attribute__((ext_vector_type(8))) short short8;
typedef __attribute__((ext_vector_type(4))) short sv4;
typedef __attribute__((ext_vector_type(4))) float f32x4;

// Compiler-native bf16 RNE cast (fuses to v_cvt_pk_bf16_f32; m240: don't hand-roll)
__device__ inline short f2bf(float f) {
    return (short)__bfloat16_as_ushort(__float2bfloat16(f));
}
__device__ inline float bf2f(short s) {
    unsigned u = ((unsigned)(unsigned short)s) << 16;
    return __builtin_bit_cast(float, u);
}

// ---------------- prep: weights -> bf16 [n][k] (SCALE folded); rf -> bf16 [MPAD][64] zero-padded ----------------
__global__ __launch_bounds__(256) void prep_kernel(const float* __restrict__ Wq,
                                                   const float* __restrict__ Wk,
                                                   const float* __restrict__ Wv,
                                                   const float* __restrict__ Wfc,
                                                   const float* __restrict__ rf,
                                                   short* __restrict__ Wqt,
                                                   short* __restrict__ Wkt,
                                                   short* __restrict__ Wvt,
                                                   short* __restrict__ Wfct,
                                                   short* __restrict__ rfb) {
    int wsel = blockIdx.z;
    int tid = threadIdx.x;
    if (wsel == 4) {
        if (blockIdx.x != 0) return;
        int r0 = blockIdx.y * 36;
        for (int lp = 0; lp < 9; ++lp) {
            int c = tid + lp * 256;          // 2304 = 36 rows * 64 cols
            int r = r0 + c / 64, d = c % 64;
            float v = (r < MFEAT) ? rf[(size_t)r * DK + d] : 0.f;
            rfb[(size_t)r * DK + d] = f2bf(v);
        }
        return;
    }
    __shared__ short T[64][65];
    int k0 = blockIdx.x * 64, n0 = blockIdx.y * 64;
    const float* W = (wsel == 0) ? Wq : (wsel == 1) ? Wk : (wsel == 2) ? Wv : Wfc;
    short* Wt = (wsel == 0) ? Wqt : (wsel == 1) ? Wkt : (wsel == 2) ? Wvt : Wfct;
    float scale = (wsel <= 1) ? SCALE : 1.f;
    for (int lp = 0; lp < 4; ++lp) {
        int c = tid + lp * 256;             // 1024 = 64 k-rows * 16 n-quads
        int kk = c >> 4, q4 = (c & 15) * 4;
        f32x4 v = *(const f32x4*)&W[(size_t)(k0 + kk) * DMODEL + n0 + q4];
        for (int j = 0; j < 4; ++j) T[q4 + j][kk] = f2bf(v[j] * scale);
    }
    __syncthreads();
    for (int lp = 0; lp < 2; ++lp) {
        int c = tid + lp * 256;             // 512 = 64 n-rows * 8 k-chunks
        int nn = c >> 3, c8 = c & 7;
        short8 v = *(const short8*)&T[nn][c8 * 8];
        *(short8*)&Wt[(size_t)(n0 + nn) * DMODEL + k0 + c8 * 8] = v;
    }
}

// ============ fused QKV GEMM + random-feature map ============
// grid (nt=32, h=8, z=3). GEMM: reg-prefetch + dbuf LDS, one barrier/iter.
// feat: rf fragments from pre-converted bf16 rfb (2 short8 loads/tr, zero cvt).
__global__ __launch_bounds__(256) void qkvfeat_kernel(const float* __restrict__ qx,
                                                      const float* __restrict__ kx,
                                                      const float* __restrict__ vx,
                                                      const short* __restrict__ Wqt,
                                                      const short* __restrict__ Wkt,
                                                      const short* __restrict__ Wvt,
                                                      const float* __restrict__ gamma,
                                                      const float* __restrict__ beta,
                                                      const short* __restrict__ rfb,
                                                      short* __restrict__ vh,
                                                      short* __restrict__ qp,
                                                      short* __restrict__ kp) {
    __shared__ __align__(16) char smem[38656];
    auto AsB = (short(*)[40])smem;             // [128][40]: double-buffered A
    auto BsB = (short(*)[40])(smem + 10240);   // [128][40]: double-buffered B
    auto Xs = (short(*)[72])smem;              // feat input (overlays after GEMM)
    short* kpl = (short*)smem;                 // 64x300 output staging
    float* hks = (float*)(smem + 38400);       // 64 floats

    int z = blockIdx.z;
    const float* A = (z == 0) ? qx : (z == 1) ? kx : vx;
    const short* Bt = (z == 0) ? Wqt : (z == 1) ? Wkt : Wvt;
    int nt = blockIdx.x, h = blockIdx.y;
    int bm = nt * 64, bn = h * 64, n0 = nt * 64;
    int tid = threadIdx.x;
    int wid = tid >> 6, lane = tid & 63;
    f32x4 acc[4] = {f32x4{0,0,0,0}, f32x4{0,0,0,0}, f32x4{0,0,0,0}, f32x4{0,0,0,0}};
    int ar = tid >> 2, akq = tid & 3;
    float lnm = 0.f, lnr = 0.f;
    if (z == 0) {
        const float* xr = qx + (size_t)(bm + ar) * DMODEL + akq * 128;
        float s = 0.f, ss = 0.f;
#pragma unroll 4
        for (int i = 0; i < 128; i += 4) {
            f32x4 vv = *(const f32x4*)(xr + i);
            s += vv[0] + vv[1] + vv[2] + vv[3];
            ss += vv[0]*vv[0] + vv[1]*vv[1] + vv[2]*vv[2] + vv[3]*vv[3];
        }
        s += __shfl_xor(s, 1); s += __shfl_xor(s, 2);
        ss += __shfl_xor(ss, 1); ss += __shfl_xor(ss, 2);
        float m = s / (float)DMODEL;
        float var = ss / (float)DMODEL - m * m;
        lnm = m;
        lnr = rsqrtf(var + LN_EPS);
    }
    auto loadA = [&](int k0) -> short8 {
        const float* src = A + (size_t)(bm + ar) * DMODEL + k0 + akq * 8;
        f32x4 v0 = *(const f32x4*)src;
        f32x4 v1 = *(const f32x4*)(src + 4);
        short8 sv;
        if (z == 0) {
            f32x4 g0 = *(const f32x4*)&gamma[k0 + akq * 8];
            f32x4 g1 = *(const f32x4*)&gamma[k0 + akq * 8 + 4];
            f32x4 bb0 = *(const f32x4*)&beta[k0 + akq * 8];
            f32x4 bb1 = *(const f32x4*)&beta[k0 + akq * 8 + 4];
            for (int j = 0; j < 4; ++j) {
                sv[j] = f2bf((v0[j] - lnm) * lnr * g0[j] + bb0[j]);
                sv[4 + j] = f2bf((v1[j] - lnm) * lnr * g1[j] + bb1[j]);
            }
        } else {
            for (int j = 0; j < 4; ++j) { sv[j] = f2bf(v0[j]); sv[4 + j] = f2bf(v1[j]); }
        }
        return sv;
    };
    auto loadB = [&](int k0) -> short8 {
        return *(const short8*)&Bt[(size_t)(bn + ar) * DMODEL + k0 + akq * 8];
    };
    short8 aReg = loadA(0), bReg = loadB(0);
    int buf = 0;
#pragma unroll 2
    for (int k0 = 0; k0 < DMODEL; k0 += 32) {
        *(short8*)&AsB[buf * 64 + ar][akq * 8] = aReg;
        *(short8*)&BsB[buf * 64 + ar][akq * 8] = bReg;
        __syncthreads();
        if (k0 + 32 < DMODEL) { aReg = loadA(k0 + 32); bReg = loadB(k0 + 32); }
        int row = buf * 64 + wid * 16 + (lane & 15);
        int koff = (lane >> 4) * 8;
        short8 a = *(const short8*)&AsB[row][koff];
        for (int nf = 0; nf < 4; ++nf) {
            int col = buf * 64 + nf * 16 + (lane & 15);
            short8 b = *(const short8*)&BsB[col][koff];
            acc[nf] = __builtin_amdgcn_mfma_f32_16x16x32_bf16(a, b, acc[nf], 0, 0, 0);
        }
        buf ^= 1;
    }
    __syncthreads();   // all waves done with LDS before feat-phase overlay / exit
    if (z == 2) {
        for (int nf = 0; nf < 4; ++nf) {
            int col = bn + nf * 16 + (lane & 15);
            for (int j = 0; j < 4; ++j) {
                int row = bm + wid * 16 + (lane >> 4) * 4 + j;
                vh[(size_t)row * DMODEL + col] = f2bf(acc[nf][j]);
            }
        }
        return;
    }
    // ---- feat phase: C tile -> Xs (bf16) ----
    for (int nf = 0; nf < 4; ++nf) {
        int col = nf * 16 + (lane & 15);
        for (int j = 0; j < 4; ++j) {
            int row = wid * 16 + (lane >> 4) * 4 + j;
            Xs[row][col] = f2bf(acc[nf][j]);
        }
    }
    if (z == 1) {
        for (int j = 0; j < 4; ++j) {
            float ss = 0.f;
            for (int nf = 0; nf < 4; ++nf) ss += acc[nf][j] * acc[nf][j];
            for (int o = 1; o < 16; o <<= 1) ss += __shfl_xor(ss, o);
            if ((lane & 15) == 0) hks[wid * 16 + (lane >> 4) * 4 + j] = -0.5f * ss;
        }
    }
    __syncthreads();

    int w = wid, l = lane;
    int fr = l & 15, fq = (l >> 4) * 8;
    short8 xb0 = *(const short8*)&Xs[w * 16 + fr][fq];
    short8 xb1 = *(const short8*)&Xs[w * 16 + fr][32 + fq];
    int n_loc = w * 16 + fr;
    float hval = (z == 1) ? hks[n_loc] : 0.f;
    __syncthreads();  // xb/hks reads done; Xs region becomes kpl

    short (*kpl2)[300] = (short(*)[300])kpl;
    const float cnorm = 0.06131393394849658f;  // 266^-0.5
#pragma unroll
    for (int tr = 0; tr < 18; ++tr) {
        int row = tr * 16 + fr;
        short8 a0 = *(const short8*)&rfb[(size_t)row * DK + fq];
        short8 a1 = *(const short8*)&rfb[(size_t)row * DK + 32 + fq];
        f32x4 facc = {0.f, 0.f, 0.f, 0.f};
        facc = __builtin_amdgcn_mfma_f32_16x16x32_bf16(a0, xb0, facc, 0, 0, 0);
        facc = __builtin_amdgcn_mfma_f32_16x16x32_bf16(a1, xb1, facc, 0, 0, 0);
        sv4 o;
        for (int j = 0; j < 4; ++j) {
            int m = tr * 16 + (l >> 4) * 4 + j;
            float val = (m < MFEAT) ? cnorm * (__expf(facc[j] + hval) + KERNEL_EPS) : 0.f;
            o[j] = f2bf(val);
        }
        *(sv4*)&kpl2[n_loc][tr * 16 + (l >> 4) * 4] = o;
    }
    __syncthreads();
    short* outp = (z == 0) ? qp : kp;
    for (int lp = 0; lp < 9; ++lp) {
        int c = tid + lp * 256;      // 64 rows * 36 chunks
        int nn = c / 36, c8 = c % 36;
        short8 v = *(const short8*)&kpl2[nn][c8 * 8];
        *(short8*)&outp[((size_t)h * NSEQ + n0 + nn) * MPAD + c8 * 8] = v;
    }
}

// ---------------- phase A (MFMA): per-chunk sums -> bf16 KVc[(h,t,dv)][m], fp32 Ks[(h,t)][m] ----------------
__global__ __launch_bounds__(256) void chunksum_kernel(const short* __restrict__ kp,
                                                       const short* __restrict__ vh,
                                                       short* __restrict__ KVc,
                                                       float* __restrict__ Ks) {
    int t = blockIdx.x, h = blockIdx.y;
    __shared__ short kpT[288 * 72];   // [m][i-swizzled], stride 72 shorts (144B); 41.5KB
    __shared__ short Vt[64][72];      // [dv][i]
    int tid = threadIdx.x;
    int w = tid >> 6, l = tid & 63;
    int fr = l & 15, fq8 = (l >> 4) * 8;
    const short* kpb = kp + ((size_t)h * NSEQ + (size_t)t * 64) * MPAD;

    for (int lp = 0; lp < 9; ++lp) {
        int c = tid + lp * 256;       // 2304 = 64 i * 36 m-chunks
        int i = c / 36, c8 = c % 36;
        short8 v = *(const short8*)&kpb[(size_t)i * MPAD + c8 * 8];
        int i8 = i >> 3, i7 = i & 7;
        for (int jj = 0; jj < 8; ++jj) {
            int m = c8 * 8 + jj;
            int ig = i8 ^ ((m >> 3) & 7);
            kpT[m * 72 + ig * 8 + i7] = v[jj];
        }
    }
    for (int lp = 0; lp < 2; ++lp) {
        int c = tid + lp * 256;       // 512 = 64 i * 8 d-chunks
        int i = c & 63, d8 = (c >> 6) * 8;
        short8 v = *(const short8*)&vh[(size_t)(t * 64 + i) * DMODEL + h * DV + d8];
        for (int jj = 0; jj < 8; ++jj) Vt[d8 + jj][i] = v[jj];
    }
    __syncthreads();

    f32x4 acc[5][4];
#pragma unroll
    for (int tt = 0; tt < 5; ++tt)
        for (int nf = 0; nf < 4; ++nf) acc[tt][nf] = f32x4{0, 0, 0, 0};
#pragma unroll
    for (int tt = 0; tt < 5; ++tt) {
        int tr = w + tt * 4;
        if (tr < 18) {
            int row = tr * 16 + fr;
            int swz = (row >> 3) & 7;
            short8 a0 = *(const short8*)&kpT[row * 72 + (((fq8 >> 3)) ^ swz) * 8];
            short8 a1 = *(const short8*)&kpT[row * 72 + ((4 + (fq8 >> 3)) ^ swz) * 8];
            for (int nf = 0; nf < 4; ++nf) {
                short8 b0 = *(const short8*)&Vt[nf * 16 + fr][fq8];
                short8 b1 = *(const short8*)&Vt[nf * 16 + fr][32 + fq8];
                acc[tt][nf] = __builtin_amdgcn_mfma_f32_16x16x32_bf16(a0, b0, acc[tt][nf], 0, 0, 0);
                acc[tt][nf] = __builtin_amdgcn_mfma_f32_16x16x32_bf16(a1, b1, acc[tt][nf], 0, 0, 0);
            }
        }
    }
    for (int m = tid; m < MPAD; m += 256) {
        int swz = (m >> 3) & 7;
        float s = 0.f;
        for (int i8 = 0; i8 < 8; ++i8) {
            int ig = i8 ^ swz;
            for (int j = 0; j < 8; ++j) s += bf2f(kpT[m * 72 + ig * 8 + j]);
        }
        Ks[((size_t)h * NT + t) * MPAD + m] = s;
    }
    __syncthreads();  // kpT reads done; overlay kvT
    short* kvT = kpT; // [64 dv][296 m]
#pragma unroll
    for (int tt = 0; tt < 5; ++tt) {
        int tr = w + tt * 4;
        if (tr < 18) {
            for (int nf = 0; nf < 4; ++nf) {
                int dv = nf * 16 + fr;
                for (int j = 0; j < 4; ++j) {
                    int m = tr * 16 + (l >> 4) * 4 + j;
                    kvT[dv * 296 + m] = f2bf(acc[tt][nf][j]);
                }
            }
        }
    }
    __syncthreads();
    for (int lp = 0; lp < 9; ++lp) {
        int c = tid + lp * 256;       // 2304 = 64 dv * 36
        int dv = c / 36, c8 = c % 36;
        short8 v = *(const short8*)&kvT[dv * 296 + c8 * 8];
        *(short8*)&KVc[(((size_t)h * NT + t) * DV + dv) * MPAD + c8 * 8] = v;
    }
}

// ---------------- fused exclusive chunk-scans, batched loads ----------------
__global__ __launch_bounds__(256) void scan_kernel(const short* __restrict__ KVc,
                                                   short* __restrict__ KVbT,
                                                   float* __restrict__ Ks,
                                                   float* __restrict__ Ktot) {
    int idx = blockIdx.x * 256 + threadIdx.x;
    const int NKV = NHEAD * DV * MPAD;       // 147456
    if (idx < NKV) {
        int h = idx / (DV * MPAD);
        int rem = idx % (DV * MPAD);
        size_t base = (size_t)h * NT * DV * MPAD + rem;
        short vals[NT];
#pragma unroll
        for (int t = 0; t < NT; ++t) vals[t] = KVc[base + (size_t)t * DV * MPAD];
        float run = 0.f;
#pragma unroll
        for (int t = 0; t < NT; ++t) {
            KVbT[base + (size_t)t * DV * MPAD] = f2bf(run);
            run += bf2f(vals[t]);
        }
    } else {
        int j = idx - NKV;
        if (j < NHEAD * MPAD) {
            int h = j / MPAD, m = j % MPAD;
            size_t base = (size_t)h * NT * MPAD + m;
            float vals[NT];
#pragma unroll
            for (int t = 0; t < NT; ++t) vals[t] = Ks[base + (size_t)t * MPAD];
            float run = 0.f;
#pragma unroll
            for (int t = 0; t < NT; ++t) {
                Ks[base + (size_t)t * MPAD] = run;
                run += vals[t];
            }
            Ktot[(size_t)h * MPAD + m] = run;
        }
    }
}

// ---------------- phase C: MFMA intra+inter+denominators; bf16 out ----------------
__global__ __launch_bounds__(256) void phasec_kernel(const short* __restrict__ qp,
                                                     const short* __restrict__ kp,
                                                     const short* __restrict__ vh,
                                                     const short* __restrict__ KVbT,
                                                     const float* __restrict__ Ks,
                                                     const float* __restrict__ Ktot,
                                                     short* __restrict__ attn) {
    int t = blockIdx.x, h = blockIdx.y;
    __shared__ short Buf[64][296];   // Kp (QK^T phase) then St (inter phase)
    __shared__ short Vt[64][72];     // [dv][i]
    __shared__ short Am[64][72];     // masked A, bf16
    __shared__ float Ksp[MPAD], Ktp[MPAD];
    __shared__ float fscale_s[64];
    int tid = threadIdx.x;
    int w = tid >> 6, l = tid & 63;
    int fr = l & 15, fq = (l >> 4) * 8;
    const short* qpb = qp + ((size_t)h * NSEQ + (size_t)t * 64) * MPAD;
    const short* kpb = kp + ((size_t)h * NSEQ + (size_t)t * 64) * MPAD;
    const short* stb = KVbT + ((size_t)h * NT + t) * DV * MPAD;

    short8 qf[9];
#pragma unroll
    for (int ks = 0; ks < 9; ++ks)
        qf[ks] = *(const short8*)&qpb[(size_t)(w * 16 + fr) * MPAD + ks * 32 + fq];

    int srow = tid >> 2, sc4 = tid & 3;
#pragma unroll
    for (int lp = 0; lp < 9; ++lp) {
        int c = sc4 + lp * 4;
        *(short8*)&Buf[srow][c * 8] = *(const short8*)&kpb[(size_t)srow * MPAD + c * 8];
    }
    for (int lp = 0; lp < 2; ++lp) {
        int c = tid + lp * 256;
        int i = c & 63, d8 = (c >> 6) * 8;
        short8 v = *(const short8*)&vh[(size_t)(t * 64 + i) * DMODEL + h * DV + d8];
        for (int jj = 0; jj < 8; ++jj) Vt[d8 + jj][i] = v[jj];
    }
    for (int idx = tid; idx < MPAD; idx += 256) {
        Ksp[idx] = Ks[((size_t)h * NT + t) * MPAD + idx];
        Ktp[idx] = Ktot[(size_t)h * MPAD + idx];
    }
    short8 stg[9];
#pragma unroll
    for (int lp = 0; lp < 9; ++lp) {
        int c = sc4 + lp * 4;
        stg[lp] = *(const short8*)&stb[(size_t)srow * MPAD + c * 8];
    }
    __syncthreads();

    f32x4 accA[4] = {f32x4{0,0,0,0}, f32x4{0,0,0,0}, f32x4{0,0,0,0}, f32x4{0,0,0,0}};
    f32x4 accO[4] = {f32x4{0,0,0,0}, f32x4{0,0,0,0}, f32x4{0,0,0,0}, f32x4{0,0,0,0}};
#pragma unroll 3
    for (int ks = 0; ks < 9; ++ks) {
        int ko = ks * 32 + fq;
        for (int nf = 0; nf < 4; ++nf) {
            short8 bk = *(const short8*)&Buf[nf * 16 + fr][ko];
            accA[nf] = __builtin_amdgcn_mfma_f32_16x16x32_bf16(qf[ks], bk, accA[nf], 0, 0, 0);
        }
    }
    __syncthreads();
#pragma unroll
    for (int lp = 0; lp < 9; ++lp) {
        int c = sc4 + lp * 4;
        *(short8*)&Buf[srow][c * 8] = stg[lp];
    }
    for (int nf = 0; nf < 4; ++nf) {
        int col = nf * 16 + fr;
        for (int j = 0; j < 4; ++j) {
            int row = w * 16 + (l >> 4) * 4 + j;
            Am[row][col] = (col <= row) ? f2bf(accA[nf][j]) : (short)0;
        }
    }
    __syncthreads();
#pragma unroll 3
    for (int ks = 0; ks < 9; ++ks) {
        int ko = ks * 32 + fq;
        for (int nf = 0; nf < 4; ++nf) {
            short8 bs = *(const short8*)&Buf[nf * 16 + fr][ko];
            accO[nf] = __builtin_amdgcn_mfma_f32_16x16x32_bf16(qf[ks], bs, accO[nf], 0, 0, 0);
        }
    }
#pragma unroll
    for (int ks = 0; ks < 2; ++ks) {
        int ko = ks * 32 + fq;
        short8 a = *(const short8*)&Am[w * 16 + fr][ko];
        for (int nf = 0; nf < 4; ++nf) {
            short8 b = *(const short8*)&Vt[nf * 16 + fr][ko];
            accO[nf] = __builtin_amdgcn_mfma_f32_16x16x32_bf16(a, b, accO[nf], 0, 0, 0);
        }
    }
    int di = tid >> 2, dp = tid & 3;
    float dc = 0.f, df = 0.f;
    {
        const short* amrow = &Am[di][dp * 16];
        short8 s0 = *(const short8*)amrow;
        short8 s1 = *(const short8*)(amrow + 8);
        for (int j2 = 0; j2 < 8; ++j2) dc += bf2f(s0[j2]) + bf2f(s1[j2]);
    }
#pragma unroll
    for (int c8 = 0; c8 < 9; ++c8) {
        int m = dp * 72 + c8 * 8;
        short8 qv = *(const short8*)&qpb[(size_t)di * MPAD + m];
        for (int j2 = 0; j2 < 8; ++j2) {
            float qq = bf2f(qv[j2]);
            dc += qq * Ksp[m + j2];
            df += qq * Ktp[m + j2];
        }
    }
    dc += __shfl_xor(dc, 1); dc += __shfl_xor(dc, 2);
    df += __shfl_xor(df, 1); df += __shfl_xor(df, 2);
    if (dp == 0) {
        float dst = df;
        if (fabsf(dst) <= NORM_STAB) dst += 2.f * NORM_STAB;
        fscale_s[di] = (1.f / dc) / dst;
    }
    __syncthreads();
    for (int nf = 0; nf < 4; ++nf) {
        int col = nf * 16 + fr;
        for (int j = 0; j < 4; ++j) {
            int row = w * 16 + (l >> 4) * 4 + j;
            attn[((size_t)t * 64 + row) * DMODEL + h * DV + col] =
                f2bf(accO[nf][j] * fscale_s[row]);
        }
    }
}

// ---------------- final GEMM with bias + residual (A bf16, B pre-transposed bf16; pipelined) ----------------
__global__ __launch_bounds__(256) void fgemm_kernel(const short* __restrict__ A,
                                                    const short* __restrict__ Bt,
                                                    float* __restrict__ C,
                                                    const float* __restrict__ bias,
                                                    const float* __restrict__ residual) {
    __shared__ short AsB[128][40];
    __shared__ short BsB[128][40];
    int bm = blockIdx.y * 64, bn = blockIdx.x * 64;
    int tid = threadIdx.x;
    int wid = tid >> 6, lane = tid & 63;
    f32x4 acc[4] = {f32x4{0,0,0,0}, f32x4{0,0,0,0}, f32x4{0,0,0,0}, f32x4{0,0,0,0}};
    int ar = tid >> 2, akq = tid & 3;
    short8 aReg = *(const short8*)&A[(size_t)(bm + ar) * DMODEL + akq * 8];
    short8 bReg = *(const short8*)&Bt[(size_t)(bn + ar) * DMODEL + akq * 8];
    int buf = 0;
#pragma unroll 2
    for (int k0 = 0; k0 < DMODEL; k0 += 32) {
        *(short8*)&AsB[buf * 64 + ar][akq * 8] = aReg;
        *(short8*)&BsB[buf * 64 + ar][akq * 8] = bReg;
        __syncthreads();
        if (k0 + 32 < DMODEL) {
            aReg = *(const short8*)&A[(size_t)(bm + ar) * DMODEL + k0 + 32 + akq * 8];
            bReg = *(const short8*)&Bt[(size_t)(bn + ar) * DMODEL + k0 + 32 + akq * 8];
        }
        int row = buf * 64 + wid * 16 + (lane & 15);
        int koff = (lane >> 4) * 8;
        short8 a = *(const short8*)&AsB[row][koff];
        for (int nf = 0; nf < 4; ++nf) {
            int col = buf * 64 + nf * 16 + (lane & 15);
            short8 b = *(const short8*)&BsB[col][koff];
            acc[nf] = __builtin_amdgcn_mfma_f32_16x16x32_bf16(a, b, acc[nf], 0, 0, 0);
        }
        buf ^= 1;
    }
    for (int nf = 0; nf < 4; ++nf) {
        int col = bn + nf * 16 + (lane & 15);
        for (int j = 0; j < 4; ++j) {
            int row = bm + wid * 16 + (lane >> 4) * 4 + j;
            C[(size_t)row * DMODEL + col] =
                acc[nf][j] + bias[col] + residual[(size_t)row * DMODEL + col];
        }
    }
}

extern "C" void kernel_launch(void* const* d_in, const int* in_sizes, int n_in,
                              void* d_out, int out_size, void* d_ws, size_t ws_size,
                              hipStream_t stream) {
    const float* q = (const float*)d_in[0];
    const float* k = (const float*)d_in[1];
    const float* v = (const float*)d_in[2];
    const float* Wq = (const float*)d_in[3];
    const float* Wk = (const float*)d_in[4];
    const float* Wv = (const float*)d_in[5];
    const float* Wfc = (const float*)d_in[6];
    const float* bfc = (const float*)d_in[7];
    const float* gamma = (const float*)d_in[8];
    const float* beta = (const float*)d_in[9];
    const float* rf = (const float*)d_in[10];
    float* out = (float*)d_out;

    float* ws = (float*)d_ws;
    short* attn = (short*)ws;                              // bf16 2048*512
    short* vhb = attn + (size_t)NSEQ * DMODEL;             // bf16 2048*512
    short* qp = vhb + (size_t)NSEQ * DMODEL;               // bf16 8*2048*288
    short* kp = qp + (size_t)NHEAD * NSEQ * MPAD;
    short* KVc = kp + (size_t)NHEAD * NSEQ * MPAD;         // bf16 8*32*64*288
    short* KVbT = KVc + (size_t)NHEAD * NT * DV * MPAD;
    float* Ks = (float*)(KVbT + (size_t)NHEAD * NT * DV * MPAD);   // fp32 8*32*288
    float* Ktot = Ks + (size_t)NHEAD * NT * MPAD;          // 8*288
    short* Wqt = (short*)(Ktot + (size_t)NHEAD * MPAD);    // bf16 512*512 each
    short* Wkt = Wqt + (size_t)DMODEL * DMODEL;
    short* Wvt = Wkt + (size_t)DMODEL * DMODEL;
    short* Wfct = Wvt + (size_t)DMODEL * DMODEL;
    short* rfb = Wfct + (size_t)DMODEL * DMODEL;           // bf16 288*64

    dim3 gp(8, 8, 5);
    prep_kernel<<<gp, 256, 0, stream>>>(Wq, Wk, Wv, Wfc, rf, Wqt, Wkt, Wvt, Wfct, rfb);
    dim3 gq(NT, NHEAD, 3);
    qkvfeat_kernel<<<gq, 256, 0, stream>>>(q, k, v, Wqt, Wkt, Wvt, gamma, beta, rfb,
                                           vhb, qp, kp);
    dim3 ga(NT, NHEAD);
    chunksum_kernel<<<ga, 256, 0, stream>>>(kp, vhb, KVc, Ks);
    int scan_threads = NHEAD * DV * MPAD + NHEAD * MPAD;
    scan_kernel<<<(scan_threads + 255) / 256, 256, 0, stream>>>(KVc, KVbT, Ks, Ktot);
    dim3 gc(NT, NHEAD);
    phasec_kernel<<<gc, 256, 0, stream>>>(qp, kp, vhb, KVbT, Ks, Ktot, attn);
    dim3 g(DMODEL / 64, NSEQ / 64);
    fgemm_kernel<<<g, 256, 0, stream>>>(attn, Wfct, out, bfc, q);
}